// Round 1
// baseline (2373.961 us; speedup 1.0000x reference)
//
#include <hip/hip_runtime.h>
#include <hip/hip_bf16.h>
#include <cstddef>

typedef __attribute__((ext_vector_type(8))) short short8;
typedef __attribute__((ext_vector_type(4))) float f32x4;
typedef __attribute__((ext_vector_type(2))) float f32x2;
typedef unsigned short u16;
typedef unsigned int u32;

#define Bc 16
#define Tt 32
#define Hh 40
#define Ww 40
#define Fc 40
#define NPIX (Bc*Hh*Ww)   // 25600
#define BN_EPS_ 1e-3f

__device__ __forceinline__ float hsig(float x) {
    return fminf(fmaxf(0.2f * x + 0.5f, 0.0f), 1.0f);
}
__device__ __forceinline__ u16 f2b(float f) {
    __hip_bfloat16 h = __float2bfloat16(f);
    return __builtin_bit_cast(u16, h);
}
__device__ __forceinline__ float b2f(u16 u) {
    return __builtin_bit_cast(float, (u32)u << 16);
}

// ---------------------------------------------------------------------------
// Pack [Wx ; Wh] -> bf16 weights in per-wave MFMA B-fragment order:
//   idx = ((((ng*NKO2 + step)*5 + nt)*64 + lane)*8 + j)
//   n = ng*80 + nt*16 + (lane&15);  k = step*32 + (lane>>4)*8 + j
//   k -> pos = k/KPOS, cc = k%KPOS; cc<XPAD -> Wx[pos][cc][n] else Wh[pos][cc-XPAD][n]
// A wave's B-fragment load becomes ONE coalesced global_load_dwordx4.
// ---------------------------------------------------------------------------
template <int XPAD, int CIN, int NKO2>
__global__ __launch_bounds__(256) void build_wf(const float* __restrict__ Wx,
                                                const float* __restrict__ Wh,
                                                u16* __restrict__ Wf)
{
    constexpr int KPOS = XPAD + Fc;
    constexpr int K    = 9 * KPOS;
    int idx = blockIdx.x * 256 + threadIdx.x;
    if (idx >= 2 * NKO2 * 5 * 64 * 8) return;
    int j    = idx & 7;
    int lane = (idx >> 3) & 63;
    int rest = idx >> 9;
    int nt   = rest % 5;  rest /= 5;
    int step = rest % NKO2; rest /= NKO2;
    int ng   = rest;
    int n = ng * 80 + nt * 16 + (lane & 15);
    int k = step * 32 + (lane >> 4) * 8 + j;
    float v = 0.0f;
    if (k < K) {
        int pos = k / KPOS, cc = k - pos * KPOS;
        if (cc < XPAD) {
            v = (cc < CIN) ? Wx[(pos * CIN + cc) * 160 + n] : 0.0f;
        } else {
            v = Wh[(pos * Fc + (cc - XPAD)) * 160 + n];
        }
    }
    Wf[idx] = f2b(v);
}

// ---------------------------------------------------------------------------
// Barrier-free K-loop, explicitly software-pipelined 1 step ahead:
// while the 25-MFMA cluster for step s runs, step s+1's 5 B global loads
// (L2) and 5 A ds_reads are in flight. Ping-pong register buffers
// (a0/b0 vs a1/b1), NKO2 is even for both instantiations.
// ---------------------------------------------------------------------------
#define LOADB(s, b) { \
    _Pragma("unroll") for (int nt = 0; nt < 5; ++nt) \
        (b)[nt] = *reinterpret_cast<const short8*>(wf + (size_t)((s) * 5 + nt) * 512); }

#define LOADA(s, a) { \
    const int k_   = (s) * 32 + lquad * 8; \
    const int pos_ = k_ / KPOS; \
    const int cc_  = k_ - pos_ * KPOS; \
    short8 z_ = {}; \
    _Pragma("unroll") for (int mt = 0; mt < 5; ++mt) (a)[mt] = z_; \
    if (pos_ < 9) { \
        const int dy_ = pos_ / 3, dx_ = pos_ - dy_ * 3; \
        const u16* base_; int ch_, str_; \
        if (cc_ < XPAD) { base_ = Xs; ch_ = cc_;        str_ = XPAD; } \
        else            { base_ = Hs; ch_ = cc_ - XPAD; str_ = Fc;   } \
        _Pragma("unroll") for (int mt = 0; mt < 5; ++mt) \
            (a)[mt] = *reinterpret_cast<const short8*>( \
                &base_[((py[mt] + dy_) * 42 + px[mt] + dx_) * str_ + ch_]); \
    } }

#define DOMFMA(a, b) { \
    __builtin_amdgcn_s_setprio(1); \
    _Pragma("unroll") for (int mt = 0; mt < 5; ++mt) \
    _Pragma("unroll") for (int nt = 0; nt < 5; ++nt) \
        acc[mt][nt] = __builtin_amdgcn_mfma_f32_16x16x32_bf16( \
            (a)[mt], (b)[nt], acc[mt][nt], 0, 0, 0); \
    __builtin_amdgcn_s_setprio(0); }

template <int KPOS, int XPAD, int NKO2>
__device__ __forceinline__ void kloop(const u16* __restrict__ Xs,
                                      const u16* __restrict__ Hs,
                                      const u16* __restrict__ wf,
                                      const int* py, const int* px,
                                      int lquad, f32x4 acc[5][5])
{
    short8 a0[5], a1[5], b0[5], b1[5];
    LOADB(0, b0);
    LOADA(0, a0);
#pragma unroll 1
    for (int s = 0; s + 2 <= NKO2; s += 2) {
        LOADB(s + 1, b1);
        LOADA(s + 1, a1);
        DOMFMA(a0, b0);
        if (s + 2 < NKO2) {
            LOADB(s + 2, b0);
            LOADA(s + 2, a0);
        }
        DOMFMA(a1, b1);
    }
}

// ---------------------------------------------------------------------------
// Diagonal-pipelined ConvLSTM step: up to 4 (layer,t) stages per launch.
// Per stage: 160 blocks, M-tile 160 pixels (4 rows), N=160 gates.
// launch_bounds(256,2): VGPR cap 256 so the ping-pong pipeline fits without
// spills (acc 100 + 4x20 frag buffers + addressing ~= 220). 2 blocks/CU.
// ---------------------------------------------------------------------------
struct Stage {
    const void* xin;   // l==0: fp32 input base; l>=1: bf16 X-ring slot
    const u16* hin;    // bf16 [NPIX][40]
    u16*       hout;
    float*     cst;    // fp32 [NPIX][40]
    const u16* wf;     // fragment-ordered weights
    const float* bias; const float* ga; const float* be;
    const float* mu;   const float* va;
    u16*       xout;
    int layer; int t;
};
struct DiagArgs { Stage s[4]; };

__global__ __launch_bounds__(256, 2) void diag_step(DiagArgs args)
{
    // max(halo 40320 B, zs 160*82*4 = 52480 B) -> 52.5 KB
    __shared__ __align__(16) u16 smem[26240];

    const int sidx = blockIdx.x / 160;
    const int blk  = blockIdx.x - sidx * 160;
    const Stage& st = args.s[sidx];
    const int l    = st.layer;
    const int XPAD = (l == 0) ? 8 : 40;

    u16* Xs = smem;
    u16* Hs = smem + 6 * 42 * XPAD;
    float* zs = reinterpret_cast<float*>(smem);   // epilogue overlay, col-major stride 82

    const int tid   = threadIdx.x;
    const int P0    = blk * 160;
    const int bimg  = P0 / 1600;
    const int P0l   = P0 - bimg * 1600;
    const int P0row = P0l / 40;            // 0,4,...,36

    // ---- stage Hs halo: 6 rows x 42 cols x 40 ch ----
    const u16* hp = st.hin + (size_t)bimg * 1600 * Fc;
    for (int i = tid; i < 6 * 40 * 10; i += 256) {
        int s = i / 400, rem = i - s * 400;
        int px_ = rem / 10, c4 = rem - px_ * 10;
        int gy = P0row - 1 + s;
        uint2 v = make_uint2(0u, 0u);
        if (gy >= 0 && gy < Hh)
            v = *reinterpret_cast<const uint2*>(hp + ((size_t)gy * Ww + px_) * Fc + c4 * 4);
        *reinterpret_cast<uint2*>(&Hs[(s * 42 + px_ + 1) * Fc + c4 * 4]) = v;
    }
    for (int i = tid; i < 6 * 2 * 10; i += 256) {
        int s = i / 20, rem = i - s * 20;
        int side = rem / 10, c4 = rem - side * 10;
        *reinterpret_cast<uint2*>(&Hs[(s * 42 + (side ? 41 : 0)) * Fc + c4 * 4]) =
            make_uint2(0u, 0u);
    }

    // ---- stage Xs halo ----
    if (l == 0) {
        const float* xf = (const float*)st.xin + (size_t)(bimg * Tt + st.t) * 1600;
        for (int i = tid; i < 6 * 42; i += 256) {
            int s = i / 42, xc = i - s * 42;
            int gy = P0row - 1 + s, gx = xc - 1;
            u16 tmp[8] = {0, 0, 0, 0, 0, 0, 0, 0};
            if (gy >= 0 && gy < Hh && gx >= 0 && gx < Ww)
                tmp[0] = f2b(xf[(size_t)gy * Ww + gx]);
            *reinterpret_cast<uint4*>(&Xs[(s * 42 + xc) * 8]) =
                *reinterpret_cast<const uint4*>(tmp);
        }
    } else {
        const u16* xb = (const u16*)st.xin + (size_t)bimg * 1600 * Fc;
        for (int i = tid; i < 6 * 40 * 10; i += 256) {
            int s = i / 400, rem = i - s * 400;
            int px_ = rem / 10, c4 = rem - px_ * 10;
            int gy = P0row - 1 + s;
            uint2 v = make_uint2(0u, 0u);
            if (gy >= 0 && gy < Hh)
                v = *reinterpret_cast<const uint2*>(xb + ((size_t)gy * Ww + px_) * Fc + c4 * 4);
            *reinterpret_cast<uint2*>(&Xs[(s * 42 + px_ + 1) * Fc + c4 * 4]) = v;
        }
        for (int i = tid; i < 6 * 2 * 10; i += 256) {
            int s = i / 20, rem = i - s * 20;
            int side = rem / 10, c4 = rem - side * 10;
            *reinterpret_cast<uint2*>(&Xs[(s * 42 + (side ? 41 : 0)) * Fc + c4 * 4]) =
                make_uint2(0u, 0u);
        }
    }

    // ---- wave constants ----
    const int lane  = tid & 63;
    const int wid   = tid >> 6;
    const int mg    = wid & 1;
    const int ng    = wid >> 1;
    const int lcol  = lane & 15;
    const int lquad = lane >> 4;

    int py[5], px[5];
#pragma unroll
    for (int mt = 0; mt < 5; ++mt) {
        int mrow = mg * 80 + mt * 16 + lcol;
        py[mt] = mrow / 40;
        px[mt] = mrow - py[mt] * 40;
    }

    f32x4 acc[5][5] = {};

    __syncthreads();   // halos staged; K-loop is barrier-free

    if (l == 0) {
        const u16* wf = st.wf + ((size_t)ng * 14 * 5 + 0) * 512 + (size_t)lane * 8;
        kloop<48, 8, 14>(Xs, Hs, wf, py, px, lquad, acc);
    } else {
        const u16* wf = st.wf + ((size_t)ng * 24 * 5 + 0) * 512 + (size_t)lane * 8;
        kloop<80, 40, 24>(Xs, Hs, wf, py, px, lquad, acc);
    }

    __syncthreads();   // all waves done reading halo LDS before zs overlay

    // ---- epilogue in two 80-row chunks (zs overlays smem, col-major [160][82]) ----
    u16* hob = st.hout;
    float* cb = st.cst;
    u16* xob = (l == 3)
        ? st.xout + ((size_t)(bimg * Tt + st.t) * 1600 + P0l) * Fc
        : st.xout + ((size_t)bimg * 1600 + P0l) * Fc;

    for (int q = 0; q < 2; ++q) {
        if (mg == q) {
#pragma unroll
            for (int mt = 0; mt < 5; ++mt)
#pragma unroll
                for (int nt = 0; nt < 5; ++nt) {
                    int mr   = mt * 16 + lquad * 4;
                    int ncol = ng * 80 + nt * 16 + lcol;
                    f32x2 lo, hi;
                    lo[0] = acc[mt][nt][0]; lo[1] = acc[mt][nt][1];
                    hi[0] = acc[mt][nt][2]; hi[1] = acc[mt][nt][3];
                    // stride 82 dwords == 18 mod 32 banks: b64 writes conflict-free
                    *reinterpret_cast<f32x2*>(&zs[ncol * 82 + mr])     = lo;
                    *reinterpret_cast<f32x2*>(&zs[ncol * 82 + mr + 2]) = hi;
                }
        }
        __syncthreads();
        for (int i = tid; i < 3200; i += 256) {
            int m = i / 40, f = i - m * 40;
            float zi = zs[f * 82 + m]          + st.bias[f];
            float zf = zs[(40 + f) * 82 + m]   + st.bias[40 + f];
            float zg = zs[(80 + f) * 82 + m]   + st.bias[80 + f];
            float zo = zs[(120 + f) * 82 + m]  + st.bias[120 + f];
            int pl = q * 80 + m;
            size_t gp = (size_t)(P0 + pl) * Fc + f;
            float cold = cb[gp];
            float cn = hsig(zf) * cold + hsig(zi) * tanhf(zg);
            float hn = hsig(zo) * tanhf(cn);
            cb[gp] = cn;
            hob[gp] = f2b(hn);
            float sc = st.ga[f] * rsqrtf(st.va[f] + BN_EPS_);
            xob[(size_t)pl * Fc + f] = f2b((hn - st.mu[f]) * sc + st.be[f]);
        }
        __syncthreads();   // zs reads done before next chunk's overwrite
    }
}

// ---------------------------------------------------------------------------
// Conv3D (3x3x3 SAME) + bias + sigmoid, bf16 in, fp32 out.
// t-blocked: each thread computes 4 consecutive t outputs for one pixel, so
// each of the 6 contributing t-slices is loaded+converted ONCE and reused by
// up to 3 outputs; FMAs issue as packed v_pk_fma_f32 (2 ch/instr).
// ---------------------------------------------------------------------------
__global__ __launch_bounds__(320) void conv3d_sig_bf16(
    const u16* __restrict__ X,        // bf16 [B,T,1600,40]
    const float* __restrict__ W3,     // [3,3,3,40,1]
    const float* __restrict__ b3,
    float* __restrict__ out)          // [B,T,1600]
{
    __shared__ float ws[27 * Fc];
    for (int i = threadIdx.x; i < 27 * Fc; i += 320) ws[i] = W3[i];
    __syncthreads();

    const int bid   = blockIdx.x;           // 640 blocks
    const int xcd   = bid & 7;
    const int local = bid >> 3;             // 0..79
    const int b     = xcd * 2 + (local / 40);
    const int rem   = local - (local / 40) * 40;
    const int tg    = rem / 5;              // 0..7 -> t0 = 4*tg
    const int s     = rem - tg * 5;
    const int t0    = tg * 4;
    const int pix   = s * 320 + threadIdx.x;
    const int y     = pix / 40;
    const int x     = pix - y * 40;

    f32x2 acc0 = {0.f, 0.f}, acc1 = {0.f, 0.f}, acc2v = {0.f, 0.f}, acc3 = {0.f, 0.f};

    for (int tc = t0 - 1; tc <= t0 + 4; ++tc) {
        if (tc < 0 || tc >= Tt) continue;
        for (int dy = 0; dy < 3; ++dy) {
            int yy = y + dy - 1;
            if (yy < 0 || yy >= Hh) continue;
            for (int dx = 0; dx < 3; ++dx) {
                int xx = x + dx - 1;
                if (xx < 0 || xx >= Ww) continue;
                const u16* xp = X + ((size_t)(b * Tt + tc) * 1600 + yy * 40 + xx) * Fc;
                f32x2 xv[20];
#pragma unroll
                for (int p = 0; p < 10; ++p) {
                    ushort4 v = *reinterpret_cast<const ushort4*>(xp + p * 4);
                    xv[2 * p][0]     = b2f(v.x); xv[2 * p][1]     = b2f(v.y);
                    xv[2 * p + 1][0] = b2f(v.z); xv[2 * p + 1][1] = b2f(v.w);
                }
#pragma unroll
                for (int i = 0; i < 4; ++i) {
                    const int dt = tc - t0 - i + 1;      // uniform per block
                    if (dt < 0 || dt > 2) continue;
                    const float* wp = ws + ((dt * 3 + dy) * 3 + dx) * Fc;
                    f32x2& A = (i == 0) ? acc0 : (i == 1) ? acc1 : (i == 2) ? acc2v : acc3;
#pragma unroll
                    for (int p = 0; p < 20; ++p) {
                        f32x2 w2 = *reinterpret_cast<const f32x2*>(wp + 2 * p);
                        asm("v_pk_fma_f32 %0, %1, %2, %0" : "+v"(A) : "v"(xv[p]), "v"(w2));
                    }
                }
            }
        }
    }

    const float bias = b3[0];
#pragma unroll
    for (int i = 0; i < 4; ++i) {
        const f32x2& A = (i == 0) ? acc0 : (i == 1) ? acc1 : (i == 2) ? acc2v : acc3;
        float r = A[0] + A[1] + bias;
        out[((size_t)(b * Tt + t0 + i) * 1600 + pix)] = 1.0f / (1.0f + expf(-r));
    }
}

// ---------------------------------------------------------------------------
extern "C" void kernel_launch(void* const* d_in, const int* in_sizes, int n_in,
                              void* d_out, int out_size, void* d_ws, size_t ws_size,
                              hipStream_t stream)
{
    const float* inp = (const float*)d_in[0];

    char* p = (char*)d_ws;
    const size_t x3sz   = (size_t)Bc * Tt * 1600 * Fc * sizeof(u16);  // 65,536,000
    const size_t slotsz = (size_t)Bc * 1600 * Fc * sizeof(u16);       //  2,048,000
    const size_t csz    = (size_t)NPIX * Fc * sizeof(float);          //  4,096,000
    const size_t wfsz   = (size_t)2 * 24 * 5 * 64 * 8 * sizeof(u16);  //    245,760

    u16* X3 = (u16*)p;                       p += x3sz;
    u16* xr[3];
    for (int l = 0; l < 3; ++l) { xr[l] = (u16*)p; p += 2 * slotsz; }
    u16* hb[8];
    for (int i = 0; i < 8; ++i) { hb[i] = (u16*)p; p += slotsz; }
    float* cbuf[4];
    for (int l = 0; l < 4; ++l) { cbuf[l] = (float*)p; p += csz; }
    u16* wf[4];
    for (int l = 0; l < 4; ++l) { wf[l] = (u16*)p; p += wfsz; }
    // total ~112 MB

    for (int l = 0; l < 4; ++l) {
        const float* Wx = (const float*)d_in[1 + 7 * l + 0];
        const float* Wh = (const float*)d_in[1 + 7 * l + 1];
        if (l == 0)
            build_wf<8, 1, 14><<<(2 * 14 * 5 * 512 + 255) / 256, 256, 0, stream>>>(Wx, Wh, wf[l]);
        else
            build_wf<40, 40, 24><<<(2 * 24 * 5 * 512 + 255) / 256, 256, 0, stream>>>(Wx, Wh, wf[l]);
        hipMemsetAsync(hb[l * 2], 0, slotsz, stream);
        hipMemsetAsync(cbuf[l], 0, csz, stream);
    }

    // ---- 35 diagonals: d = l + t ----
    for (int d = 0; d < Tt + 3; ++d) {
        DiagArgs da;
        int na = 0;
        for (int l = 0; l < 4; ++l) {
            int t = d - l;
            if (t < 0 || t >= Tt) continue;
            Stage& s = da.s[na++];
            s.layer = l; s.t = t;
            s.hin  = hb[l * 2 + (t & 1)];
            s.hout = hb[l * 2 + ((t + 1) & 1)];
            s.cst  = cbuf[l];
            s.wf   = wf[l];
            s.bias = (const float*)d_in[1 + 7 * l + 2];
            s.ga   = (const float*)d_in[1 + 7 * l + 3];
            s.be   = (const float*)d_in[1 + 7 * l + 4];
            s.mu   = (const float*)d_in[1 + 7 * l + 5];
            s.va   = (const float*)d_in[1 + 7 * l + 6];
            s.xin  = (l == 0) ? (const void*)inp
                              : (const void*)(xr[l - 1] + (size_t)(t & 1) * (slotsz / 2));
            s.xout = (l == 3) ? X3 : xr[l] + (size_t)(t & 1) * (slotsz / 2);
        }
        diag_step<<<na * 160, 256, 0, stream>>>(da);
    }

    conv3d_sig_bf16<<<640, 320, 0, stream>>>(
        X3, (const float*)d_in[29], (const float*)d_in[30], (float*)d_out);
}

// Round 2
// 1882.726 us; speedup vs baseline: 1.2609x; 1.2609x over previous
//
#include <hip/hip_runtime.h>
#include <hip/hip_bf16.h>
#include <cstddef>

typedef __attribute__((ext_vector_type(8))) short short8;
typedef __attribute__((ext_vector_type(4))) float f32x4;
typedef __attribute__((ext_vector_type(2))) float f32x2;
typedef unsigned short u16;
typedef unsigned int u32;

#define Bc 16
#define Tt 32
#define Hh 40
#define Ww 40
#define Fc 40
#define NPIX (Bc*Hh*Ww)   // 25600
#define BN_EPS_ 1e-3f

__device__ __forceinline__ float hsig(float x) {
    return fminf(fmaxf(0.2f * x + 0.5f, 0.0f), 1.0f);
}
__device__ __forceinline__ u16 f2b(float f) {
    __hip_bfloat16 h = __float2bfloat16(f);
    return __builtin_bit_cast(u16, h);
}
__device__ __forceinline__ float b2f(u16 u) {
    return __builtin_bit_cast(float, (u32)u << 16);
}

// ---------------------------------------------------------------------------
// Pack [Wx ; Wh] -> bf16 weights in per-wave MFMA B-fragment order:
//   idx = ((((ng*NKO2 + step)*5 + nt)*64 + lane)*8 + j)
//   n = ng*80 + nt*16 + (lane&15);  k = step*32 + (lane>>4)*8 + j
//   k -> pos = k/KPOS, cc = k%KPOS; cc<XPAD -> Wx[pos][cc][n] else Wh[pos][cc-XPAD][n]
// A wave's B-fragment load becomes ONE coalesced global_load_dwordx4.
// ---------------------------------------------------------------------------
template <int XPAD, int CIN, int NKO2>
__global__ __launch_bounds__(256) void build_wf(const float* __restrict__ Wx,
                                                const float* __restrict__ Wh,
                                                u16* __restrict__ Wf)
{
    constexpr int KPOS = XPAD + Fc;
    constexpr int K    = 9 * KPOS;
    int idx = blockIdx.x * 256 + threadIdx.x;
    if (idx >= 2 * NKO2 * 5 * 64 * 8) return;
    int j    = idx & 7;
    int lane = (idx >> 3) & 63;
    int rest = idx >> 9;
    int nt   = rest % 5;  rest /= 5;
    int step = rest % NKO2; rest /= NKO2;
    int ng   = rest;
    int n = ng * 80 + nt * 16 + (lane & 15);
    int k = step * 32 + (lane >> 4) * 8 + j;
    float v = 0.0f;
    if (k < K) {
        int pos = k / KPOS, cc = k - pos * KPOS;
        if (cc < XPAD) {
            v = (cc < CIN) ? Wx[(pos * CIN + cc) * 160 + n] : 0.0f;
        } else {
            v = Wh[(pos * Fc + (cc - XPAD)) * 160 + n];
        }
    }
    Wf[idx] = f2b(v);
}

// ---------------------------------------------------------------------------
// Barrier-free K-loop: B fragments streamed from L2 (coalesced dwordx4),
// A fragments from LDS halo. 25 MFMA per step, no __syncthreads inside.
// ROUND-0 structure (proven 51 us/diag) + s_setprio around the MFMA cluster
// (T5: barrier-free loop -> waves drift -> role diversity; isolated change).
// ---------------------------------------------------------------------------
template <int KPOS, int XPAD, int NKO2>
__device__ __forceinline__ void kloop(const u16* __restrict__ Xs,
                                      const u16* __restrict__ Hs,
                                      const u16* __restrict__ wf,
                                      const int* py, const int* px,
                                      int lquad, f32x4 acc[5][5])
{
#pragma unroll 2
    for (int step = 0; step < NKO2; ++step) {
        short8 bfr[5];
#pragma unroll
        for (int nt = 0; nt < 5; ++nt)
            bfr[nt] = *reinterpret_cast<const short8*>(wf + (size_t)(step * 5 + nt) * 512);

        const int k   = step * 32 + lquad * 8;
        const int pos = k / KPOS;             // compile-time KPOS -> magic mul
        const int cc  = k - pos * KPOS;
        short8 afr[5] = {};
        if (pos < 9) {
            const int dy = pos / 3, dx = pos - dy * 3;
            const u16* base; int ch, str;
            if (cc < XPAD) { base = Xs; ch = cc;        str = XPAD; }
            else           { base = Hs; ch = cc - XPAD; str = Fc;   }
#pragma unroll
            for (int mt = 0; mt < 5; ++mt)
                afr[mt] = *reinterpret_cast<const short8*>(
                    &base[((py[mt] + dy) * 42 + px[mt] + dx) * str + ch]);
        }
        __builtin_amdgcn_s_setprio(1);
#pragma unroll
        for (int mt = 0; mt < 5; ++mt)
#pragma unroll
            for (int nt = 0; nt < 5; ++nt)
                acc[mt][nt] = __builtin_amdgcn_mfma_f32_16x16x32_bf16(
                    afr[mt], bfr[nt], acc[mt][nt], 0, 0, 0);
        __builtin_amdgcn_s_setprio(0);
    }
}

// ---------------------------------------------------------------------------
// Diagonal-pipelined ConvLSTM step: up to 4 (layer,t) stages per launch.
// Per stage: 160 blocks, M-tile 160 pixels (4 rows), N=160 gates.
// ---------------------------------------------------------------------------
struct Stage {
    const void* xin;   // l==0: fp32 input base; l>=1: bf16 X-ring slot
    const u16* hin;    // bf16 [NPIX][40]
    u16*       hout;
    float*     cst;    // fp32 [NPIX][40]
    const u16* wf;     // fragment-ordered weights
    const float* bias; const float* ga; const float* be;
    const float* mu;   const float* va;
    u16*       xout;
    int layer; int t;
};
struct DiagArgs { Stage s[4]; };

__global__ __launch_bounds__(256, 3) void diag_step(DiagArgs args)
{
    // max(halo 40320 B, zs 80*164*4 = 52480 B) -> 52.5 KB => 3 blocks/CU
    __shared__ __align__(16) u16 smem[26240];

    const int sidx = blockIdx.x / 160;
    const int blk  = blockIdx.x - sidx * 160;
    const Stage& st = args.s[sidx];
    const int l    = st.layer;
    const int XPAD = (l == 0) ? 8 : 40;

    u16* Xs = smem;
    u16* Hs = smem + 6 * 42 * XPAD;
    float* zs = reinterpret_cast<float*>(smem);   // epilogue overlay

    const int tid   = threadIdx.x;
    const int P0    = blk * 160;
    const int bimg  = P0 / 1600;
    const int P0l   = P0 - bimg * 1600;
    const int P0row = P0l / 40;            // 0,4,...,36

    // ---- stage Hs halo: 6 rows x 42 cols x 40 ch ----
    const u16* hp = st.hin + (size_t)bimg * 1600 * Fc;
    for (int i = tid; i < 6 * 40 * 10; i += 256) {
        int s = i / 400, rem = i - s * 400;
        int px_ = rem / 10, c4 = rem - px_ * 10;
        int gy = P0row - 1 + s;
        uint2 v = make_uint2(0u, 0u);
        if (gy >= 0 && gy < Hh)
            v = *reinterpret_cast<const uint2*>(hp + ((size_t)gy * Ww + px_) * Fc + c4 * 4);
        *reinterpret_cast<uint2*>(&Hs[(s * 42 + px_ + 1) * Fc + c4 * 4]) = v;
    }
    for (int i = tid; i < 6 * 2 * 10; i += 256) {
        int s = i / 20, rem = i - s * 20;
        int side = rem / 10, c4 = rem - side * 10;
        *reinterpret_cast<uint2*>(&Hs[(s * 42 + (side ? 41 : 0)) * Fc + c4 * 4]) =
            make_uint2(0u, 0u);
    }

    // ---- stage Xs halo ----
    if (l == 0) {
        const float* xf = (const float*)st.xin + (size_t)(bimg * Tt + st.t) * 1600;
        for (int i = tid; i < 6 * 42; i += 256) {
            int s = i / 42, xc = i - s * 42;
            int gy = P0row - 1 + s, gx = xc - 1;
            u16 tmp[8] = {0, 0, 0, 0, 0, 0, 0, 0};
            if (gy >= 0 && gy < Hh && gx >= 0 && gx < Ww)
                tmp[0] = f2b(xf[(size_t)gy * Ww + gx]);
            *reinterpret_cast<uint4*>(&Xs[(s * 42 + xc) * 8]) =
                *reinterpret_cast<const uint4*>(tmp);
        }
    } else {
        const u16* xb = (const u16*)st.xin + (size_t)bimg * 1600 * Fc;
        for (int i = tid; i < 6 * 40 * 10; i += 256) {
            int s = i / 400, rem = i - s * 400;
            int px_ = rem / 10, c4 = rem - px_ * 10;
            int gy = P0row - 1 + s;
            uint2 v = make_uint2(0u, 0u);
            if (gy >= 0 && gy < Hh)
                v = *reinterpret_cast<const uint2*>(xb + ((size_t)gy * Ww + px_) * Fc + c4 * 4);
            *reinterpret_cast<uint2*>(&Xs[(s * 42 + px_ + 1) * Fc + c4 * 4]) = v;
        }
        for (int i = tid; i < 6 * 2 * 10; i += 256) {
            int s = i / 20, rem = i - s * 20;
            int side = rem / 10, c4 = rem - side * 10;
            *reinterpret_cast<uint2*>(&Xs[(s * 42 + (side ? 41 : 0)) * Fc + c4 * 4]) =
                make_uint2(0u, 0u);
        }
    }

    // ---- wave constants ----
    const int lane  = tid & 63;
    const int wid   = tid >> 6;
    const int mg    = wid & 1;
    const int ng    = wid >> 1;
    const int lcol  = lane & 15;
    const int lquad = lane >> 4;

    int py[5], px[5];
#pragma unroll
    for (int mt = 0; mt < 5; ++mt) {
        int mrow = mg * 80 + mt * 16 + lcol;
        py[mt] = mrow / 40;
        px[mt] = mrow - py[mt] * 40;
    }

    f32x4 acc[5][5] = {};

    __syncthreads();   // halos staged; K-loop is barrier-free

    if (l == 0) {
        const u16* wf = st.wf + ((size_t)ng * 14 * 5 + 0) * 512 + (size_t)lane * 8;
        kloop<48, 8, 14>(Xs, Hs, wf, py, px, lquad, acc);
    } else {
        const u16* wf = st.wf + ((size_t)ng * 24 * 5 + 0) * 512 + (size_t)lane * 8;
        kloop<80, 40, 24>(Xs, Hs, wf, py, px, lquad, acc);
    }

    __syncthreads();   // all waves done reading halo LDS before zs overlay

    // ---- epilogue in two 80-row chunks (zs overlays smem) ----
    u16* hob = st.hout;
    float* cb = st.cst;
    u16* xob = (l == 3)
        ? st.xout + ((size_t)(bimg * Tt + st.t) * 1600 + P0l) * Fc
        : st.xout + ((size_t)bimg * 1600 + P0l) * Fc;

    for (int q = 0; q < 2; ++q) {
        if (mg == q) {
#pragma unroll
            for (int mt = 0; mt < 5; ++mt)
#pragma unroll
                for (int nt = 0; nt < 5; ++nt) {
                    int mr   = mt * 16 + lquad * 4;
                    int ncol = ng * 80 + nt * 16 + lcol;
#pragma unroll
                    for (int r = 0; r < 4; ++r)
                        zs[(mr + r) * 164 + ncol] = acc[mt][nt][r];
                }
        }
        __syncthreads();
        for (int i = tid; i < 3200; i += 256) {
            int m = i / 40, f = i - m * 40;
            float zi = zs[m * 164 + f]        + st.bias[f];
            float zf = zs[m * 164 + 40 + f]   + st.bias[40 + f];
            float zg = zs[m * 164 + 80 + f]   + st.bias[80 + f];
            float zo = zs[m * 164 + 120 + f]  + st.bias[120 + f];
            int pl = q * 80 + m;
            size_t gp = (size_t)(P0 + pl) * Fc + f;
            float cold = cb[gp];
            float cn = hsig(zf) * cold + hsig(zi) * tanhf(zg);
            float hn = hsig(zo) * tanhf(cn);
            cb[gp] = cn;
            hob[gp] = f2b(hn);
            float sc = st.ga[f] * rsqrtf(st.va[f] + BN_EPS_);
            xob[(size_t)pl * Fc + f] = f2b((hn - st.mu[f]) * sc + st.be[f]);
        }
        __syncthreads();   // zs reads done before next chunk's overwrite
    }
}

// ---------------------------------------------------------------------------
// Conv3D (3x3x3 SAME) + bias + sigmoid, bf16 in, fp32 out.
// t-PAIR blocked: each thread computes 2 consecutive t outputs for one pixel.
// The 4 contributing t-slices are loaded+converted ONCE and shared by both
// outputs (loads/output 270->180, FMA+cvt/output ~2400->~1350); FMAs issue as
// packed v_pk_fma_f32. Grid stays at 1280 blocks (6.25 waves/SIMD) so the
// kernel is NOT grid-occupancy-limited (round-1 lesson: 640 blocks -> 25%).
// ---------------------------------------------------------------------------
__global__ __launch_bounds__(320) void conv3d_sig_bf16(
    const u16* __restrict__ X,        // bf16 [B,T,1600,40]
    const float* __restrict__ W3,     // [3,3,3,40,1]
    const float* __restrict__ b3,
    float* __restrict__ out)          // [B,T,1600]
{
    __shared__ float ws[27 * Fc];
    for (int i = threadIdx.x; i < 27 * Fc; i += 320) ws[i] = W3[i];
    __syncthreads();

    const int bid   = blockIdx.x;           // 1280 blocks
    const int xcd   = bid & 7;
    const int local = bid >> 3;             // 0..159
    const int b     = xcd * 2 + (local / 80);
    const int rem   = local - (local / 80) * 80;
    const int tg    = rem / 5;              // 0..15 -> t0 = 2*tg
    const int s     = rem - tg * 5;
    const int t0    = tg * 2;
    const int pix   = s * 320 + threadIdx.x;
    const int y     = pix / 40;
    const int x     = pix - y * 40;

    f32x2 acc0 = {0.f, 0.f}, acc1 = {0.f, 0.f};

#pragma unroll
    for (int j = 0; j < 4; ++j) {           // slice tc = t0-1+j
        const int tc = t0 - 1 + j;
        if (tc < 0 || tc >= Tt) continue;   // uniform per block
        for (int dy = 0; dy < 3; ++dy) {
            int yy = y + dy - 1;
            if (yy < 0 || yy >= Hh) continue;
            for (int dx = 0; dx < 3; ++dx) {
                int xx = x + dx - 1;
                if (xx < 0 || xx >= Ww) continue;
                const u16* xp = X + ((size_t)(b * Tt + tc) * 1600 + yy * 40 + xx) * Fc;
                f32x2 xv[20];
#pragma unroll
                for (int p = 0; p < 10; ++p) {
                    ushort4 v = *reinterpret_cast<const ushort4*>(xp + p * 4);
                    xv[2 * p][0]     = b2f(v.x); xv[2 * p][1]     = b2f(v.y);
                    xv[2 * p + 1][0] = b2f(v.z); xv[2 * p + 1][1] = b2f(v.w);
                }
#pragma unroll
                for (int i = 0; i < 2; ++i) {
                    const int dt = j - i;               // compile-time
                    if (dt < 0 || dt > 2) continue;
                    const float* wp = ws + ((dt * 3 + dy) * 3 + dx) * Fc;
                    f32x2& A = (i == 0) ? acc0 : acc1;
#pragma unroll
                    for (int p = 0; p < 20; ++p) {
                        f32x2 w2 = *reinterpret_cast<const f32x2*>(wp + 2 * p);
                        asm("v_pk_fma_f32 %0, %1, %2, %0" : "+v"(A) : "v"(xv[p]), "v"(w2));
                    }
                }
            }
        }
    }

    const float bias = b3[0];
#pragma unroll
    for (int i = 0; i < 2; ++i) {
        const f32x2& A = (i == 0) ? acc0 : acc1;
        float r = A[0] + A[1] + bias;
        out[((size_t)(b * Tt + t0 + i) * 1600 + pix)] = 1.0f / (1.0f + expf(-r));
    }
}

// ---------------------------------------------------------------------------
extern "C" void kernel_launch(void* const* d_in, const int* in_sizes, int n_in,
                              void* d_out, int out_size, void* d_ws, size_t ws_size,
                              hipStream_t stream)
{
    const float* inp = (const float*)d_in[0];

    char* p = (char*)d_ws;
    const size_t x3sz   = (size_t)Bc * Tt * 1600 * Fc * sizeof(u16);  // 65,536,000
    const size_t slotsz = (size_t)Bc * 1600 * Fc * sizeof(u16);       //  2,048,000
    const size_t csz    = (size_t)NPIX * Fc * sizeof(float);          //  4,096,000
    const size_t wfsz   = (size_t)2 * 24 * 5 * 64 * 8 * sizeof(u16);  //    245,760

    u16* X3 = (u16*)p;                       p += x3sz;
    u16* xr[3];
    for (int l = 0; l < 3; ++l) { xr[l] = (u16*)p; p += 2 * slotsz; }
    u16* hb[8];
    for (int i = 0; i < 8; ++i) { hb[i] = (u16*)p; p += slotsz; }
    float* cbuf[4];
    for (int l = 0; l < 4; ++l) { cbuf[l] = (float*)p; p += csz; }
    u16* wf[4];
    for (int l = 0; l < 4; ++l) { wf[l] = (u16*)p; p += wfsz; }
    // total ~112 MB

    for (int l = 0; l < 4; ++l) {
        const float* Wx = (const float*)d_in[1 + 7 * l + 0];
        const float* Wh = (const float*)d_in[1 + 7 * l + 1];
        if (l == 0)
            build_wf<8, 1, 14><<<(2 * 14 * 5 * 512 + 255) / 256, 256, 0, stream>>>(Wx, Wh, wf[l]);
        else
            build_wf<40, 40, 24><<<(2 * 24 * 5 * 512 + 255) / 256, 256, 0, stream>>>(Wx, Wh, wf[l]);
        hipMemsetAsync(hb[l * 2], 0, slotsz, stream);
        hipMemsetAsync(cbuf[l], 0, csz, stream);
    }

    // ---- 35 diagonals: d = l + t ----
    for (int d = 0; d < Tt + 3; ++d) {
        DiagArgs da;
        int na = 0;
        for (int l = 0; l < 4; ++l) {
            int t = d - l;
            if (t < 0 || t >= Tt) continue;
            Stage& s = da.s[na++];
            s.layer = l; s.t = t;
            s.hin  = hb[l * 2 + (t & 1)];
            s.hout = hb[l * 2 + ((t + 1) & 1)];
            s.cst  = cbuf[l];
            s.wf   = wf[l];
            s.bias = (const float*)d_in[1 + 7 * l + 2];
            s.ga   = (const float*)d_in[1 + 7 * l + 3];
            s.be   = (const float*)d_in[1 + 7 * l + 4];
            s.mu   = (const float*)d_in[1 + 7 * l + 5];
            s.va   = (const float*)d_in[1 + 7 * l + 6];
            s.xin  = (l == 0) ? (const void*)inp
                              : (const void*)(xr[l - 1] + (size_t)(t & 1) * (slotsz / 2));
            s.xout = (l == 3) ? X3 : xr[l] + (size_t)(t & 1) * (slotsz / 2);
        }
        diag_step<<<na * 160, 256, 0, stream>>>(da);
    }

    conv3d_sig_bf16<<<1280, 320, 0, stream>>>(
        X3, (const float*)d_in[29], (const float*)d_in[30], (float*)d_out);
}

// Round 5
// 1688.345 us; speedup vs baseline: 1.4061x; 1.1151x over previous
//
#include <hip/hip_runtime.h>
#include <hip/hip_bf16.h>
#include <cstddef>

typedef __attribute__((ext_vector_type(8))) short short8;
typedef __attribute__((ext_vector_type(4))) float f32x4;
typedef unsigned short u16;
typedef unsigned int u32;

#define Bc 16
#define Tt 32
#define Hh 40
#define Ww 40
#define Fc 40
#define NPIX (Bc*Hh*Ww)   // 25600
#define BN_EPS_ 1e-3f

__device__ __forceinline__ float hsig(float x) {
    return fminf(fmaxf(0.2f * x + 0.5f, 0.0f), 1.0f);
}
__device__ __forceinline__ u16 f2b(float f) {
    __hip_bfloat16 h = __float2bfloat16(f);
    return __builtin_bit_cast(u16, h);
}
__device__ __forceinline__ float b2f(u16 u) {
    return __builtin_bit_cast(float, (u32)u << 16);
}
// fast tanh: 1 - 2/(e^2x + 1). x=+inf -> 1, x=-inf -> -1; abs err ~1e-6,
// far below the bf16-granularity test threshold. Replaces libm tanhf.
__device__ __forceinline__ float ftanh(float x) {
    float e = __expf(2.0f * x);
    return 1.0f - __fdividef(2.0f, e + 1.0f);
}

// ---------------------------------------------------------------------------
// Pack [Wx ; Wh] -> bf16 weights in per-wave MFMA B-fragment order:
//   idx = ((((ng*NKO2 + step)*5 + nt)*64 + lane)*8 + j)
//   n = ng*80 + nt*16 + (lane&15);  k = step*32 + (lane>>4)*8 + j
//   k -> pos = k/KPOS, cc = k%KPOS; cc<XPAD -> Wx[pos][cc][n] else Wh[pos][cc-XPAD][n]
// A wave's B-fragment load becomes ONE coalesced global_load_dwordx4.
// ---------------------------------------------------------------------------
template <int XPAD, int CIN, int NKO2>
__global__ __launch_bounds__(256) void build_wf(const float* __restrict__ Wx,
                                                const float* __restrict__ Wh,
                                                u16* __restrict__ Wf)
{
    constexpr int KPOS = XPAD + Fc;
    constexpr int K    = 9 * KPOS;
    int idx = blockIdx.x * 256 + threadIdx.x;
    if (idx >= 2 * NKO2 * 5 * 64 * 8) return;
    int j    = idx & 7;
    int lane = (idx >> 3) & 63;
    int rest = idx >> 9;
    int nt   = rest % 5;  rest /= 5;
    int step = rest % NKO2; rest /= NKO2;
    int ng   = rest;
    int n = ng * 80 + nt * 16 + (lane & 15);
    int k = step * 32 + (lane >> 4) * 8 + j;
    float v = 0.0f;
    if (k < K) {
        int pos = k / KPOS, cc = k - pos * KPOS;
        if (cc < XPAD) {
            v = (cc < CIN) ? Wx[(pos * CIN + cc) * 160 + n] : 0.0f;
        } else {
            v = Wh[(pos * Fc + (cc - XPAD)) * 160 + n];
        }
    }
    Wf[idx] = f2b(v);
}

// ---------------------------------------------------------------------------
// Barrier-free K-loop: B fragments streamed from L2 (coalesced dwordx4),
// A fragments from LDS halo. 25 MFMA per step, no __syncthreads inside.
// Round-0 structure (proven ~51 us/diag) + s_setprio around the MFMA cluster
// (round-2 A/B: neutral-to-slightly-positive; kept).
// ---------------------------------------------------------------------------
template <int KPOS, int XPAD, int NKO2>
__device__ __forceinline__ void kloop(const u16* __restrict__ Xs,
                                      const u16* __restrict__ Hs,
                                      const u16* __restrict__ wf,
                                      const int* py, const int* px,
                                      int lquad, f32x4 acc[5][5])
{
#pragma unroll 2
    for (int step = 0; step < NKO2; ++step) {
        short8 bfr[5];
#pragma unroll
        for (int nt = 0; nt < 5; ++nt)
            bfr[nt] = *reinterpret_cast<const short8*>(wf + (size_t)(step * 5 + nt) * 512);

        const int k   = step * 32 + lquad * 8;
        const int pos = k / KPOS;             // compile-time KPOS -> magic mul
        const int cc  = k - pos * KPOS;
        short8 afr[5] = {};
        if (pos < 9) {
            const int dy = pos / 3, dx = pos - dy * 3;
            const u16* base; int ch, str;
            if (cc < XPAD) { base = Xs; ch = cc;        str = XPAD; }
            else           { base = Hs; ch = cc - XPAD; str = Fc;   }
#pragma unroll
            for (int mt = 0; mt < 5; ++mt)
                afr[mt] = *reinterpret_cast<const short8*>(
                    &base[((py[mt] + dy) * 42 + px[mt] + dx) * str + ch]);
        }
        __builtin_amdgcn_s_setprio(1);
#pragma unroll
        for (int mt = 0; mt < 5; ++mt)
#pragma unroll
            for (int nt = 0; nt < 5; ++nt)
                acc[mt][nt] = __builtin_amdgcn_mfma_f32_16x16x32_bf16(
                    afr[mt], bfr[nt], acc[mt][nt], 0, 0, 0);
        __builtin_amdgcn_s_setprio(0);
    }
}

// ---------------------------------------------------------------------------
// Diagonal-pipelined ConvLSTM step: up to 4 (layer,t) stages per launch.
// Per stage: 160 blocks, M-tile 160 pixels (4 rows), N=160 gates.
// ---------------------------------------------------------------------------
struct Stage {
    const void* xin;   // l==0: fp32 input base; l>=1: bf16 X-ring slot
    const u16* hin;    // bf16 [NPIX][40]
    u16*       hout;
    float*     cst;    // fp32 [NPIX][40]
    const u16* wf;     // fragment-ordered weights
    const float* bias; const float* ga; const float* be;
    const float* mu;   const float* va;
    u16*       xout;
    int layer; int t;
};
struct DiagArgs { Stage s[4]; };

__global__ __launch_bounds__(256, 3) void diag_step(DiagArgs args)
{
    // max(halo 40320 B, zs 80*164*4 = 52480 B) -> 52.5 KB => 3 blocks/CU
    __shared__ __align__(16) u16 smem[26240];

    const int sidx = blockIdx.x / 160;
    const int blk  = blockIdx.x - sidx * 160;
    const Stage& st = args.s[sidx];
    const int l    = st.layer;
    const int XPAD = (l == 0) ? 8 : 40;

    u16* Xs = smem;
    u16* Hs = smem + 6 * 42 * XPAD;
    float* zs = reinterpret_cast<float*>(smem);   // epilogue overlay

    const int tid   = threadIdx.x;
    const int P0    = blk * 160;
    const int bimg  = P0 / 1600;
    const int P0l   = P0 - bimg * 1600;
    const int P0row = P0l / 40;            // 0,4,...,36

    // ---- stage Hs halo: 6 rows x 42 cols x 40 ch ----
    const u16* hp = st.hin + (size_t)bimg * 1600 * Fc;
    for (int i = tid; i < 6 * 40 * 10; i += 256) {
        int s = i / 400, rem = i - s * 400;
        int px_ = rem / 10, c4 = rem - px_ * 10;
        int gy = P0row - 1 + s;
        uint2 v = make_uint2(0u, 0u);
        if (gy >= 0 && gy < Hh)
            v = *reinterpret_cast<const uint2*>(hp + ((size_t)gy * Ww + px_) * Fc + c4 * 4);
        *reinterpret_cast<uint2*>(&Hs[(s * 42 + px_ + 1) * Fc + c4 * 4]) = v;
    }
    for (int i = tid; i < 6 * 2 * 10; i += 256) {
        int s = i / 20, rem = i - s * 20;
        int side = rem / 10, c4 = rem - side * 10;
        *reinterpret_cast<uint2*>(&Hs[(s * 42 + (side ? 41 : 0)) * Fc + c4 * 4]) =
            make_uint2(0u, 0u);
    }

    // ---- stage Xs halo ----
    if (l == 0) {
        const float* xf = (const float*)st.xin + (size_t)(bimg * Tt + st.t) * 1600;
        for (int i = tid; i < 6 * 42; i += 256) {
            int s = i / 42, xc = i - s * 42;
            int gy = P0row - 1 + s, gx = xc - 1;
            u16 tmp[8] = {0, 0, 0, 0, 0, 0, 0, 0};
            if (gy >= 0 && gy < Hh && gx >= 0 && gx < Ww)
                tmp[0] = f2b(xf[(size_t)gy * Ww + gx]);
            *reinterpret_cast<uint4*>(&Xs[(s * 42 + xc) * 8]) =
                *reinterpret_cast<const uint4*>(tmp);
        }
    } else {
        const u16* xb = (const u16*)st.xin + (size_t)bimg * 1600 * Fc;
        for (int i = tid; i < 6 * 40 * 10; i += 256) {
            int s = i / 400, rem = i - s * 400;
            int px_ = rem / 10, c4 = rem - px_ * 10;
            int gy = P0row - 1 + s;
            uint2 v = make_uint2(0u, 0u);
            if (gy >= 0 && gy < Hh)
                v = *reinterpret_cast<const uint2*>(xb + ((size_t)gy * Ww + px_) * Fc + c4 * 4);
            *reinterpret_cast<uint2*>(&Xs[(s * 42 + px_ + 1) * Fc + c4 * 4]) = v;
        }
        for (int i = tid; i < 6 * 2 * 10; i += 256) {
            int s = i / 20, rem = i - s * 20;
            int side = rem / 10, c4 = rem - side * 10;
            *reinterpret_cast<uint2*>(&Xs[(s * 42 + (side ? 41 : 0)) * Fc + c4 * 4]) =
                make_uint2(0u, 0u);
        }
    }

    // ---- wave constants ----
    const int lane  = tid & 63;
    const int wid   = tid >> 6;
    const int mg    = wid & 1;
    const int ng    = wid >> 1;
    const int lcol  = lane & 15;
    const int lquad = lane >> 4;

    int py[5], px[5];
#pragma unroll
    for (int mt = 0; mt < 5; ++mt) {
        int mrow = mg * 80 + mt * 16 + lcol;
        py[mt] = mrow / 40;
        px[mt] = mrow - py[mt] * 40;
    }

    f32x4 acc[5][5] = {};

    __syncthreads();   // halos staged; K-loop is barrier-free

    if (l == 0) {
        const u16* wf = st.wf + ((size_t)ng * 14 * 5 + 0) * 512 + (size_t)lane * 8;
        kloop<48, 8, 14>(Xs, Hs, wf, py, px, lquad, acc);
    } else {
        const u16* wf = st.wf + ((size_t)ng * 24 * 5 + 0) * 512 + (size_t)lane * 8;
        kloop<80, 40, 24>(Xs, Hs, wf, py, px, lquad, acc);
    }

    __syncthreads();   // all waves done reading halo LDS before zs overlay

    // ---- epilogue in two 80-row chunks (zs overlays smem) ----
    u16* hob = st.hout;
    float* cb = st.cst;
    u16* xob = (l == 3)
        ? st.xout + ((size_t)(bimg * Tt + st.t) * 1600 + P0l) * Fc
        : st.xout + ((size_t)bimg * 1600 + P0l) * Fc;

    for (int q = 0; q < 2; ++q) {
        if (mg == q) {
#pragma unroll
            for (int mt = 0; mt < 5; ++mt)
#pragma unroll
                for (int nt = 0; nt < 5; ++nt) {
                    int mr   = mt * 16 + lquad * 4;
                    int ncol = ng * 80 + nt * 16 + lcol;
#pragma unroll
                    for (int r = 0; r < 4; ++r)
                        zs[(mr + r) * 164 + ncol] = acc[mt][nt][r];
                }
        }
        __syncthreads();
        for (int i = tid; i < 3200; i += 256) {
            int m = i / 40, f = i - m * 40;
            float zi = zs[m * 164 + f]        + st.bias[f];
            float zf = zs[m * 164 + 40 + f]   + st.bias[40 + f];
            float zg = zs[m * 164 + 80 + f]   + st.bias[80 + f];
            float zo = zs[m * 164 + 120 + f]  + st.bias[120 + f];
            int pl = q * 80 + m;
            size_t gp = (size_t)(P0 + pl) * Fc + f;
            float cold = cb[gp];
            float cn = hsig(zf) * cold + hsig(zi) * ftanh(zg);
            float hn = hsig(zo) * ftanh(cn);
            cb[gp] = cn;
            hob[gp] = f2b(hn);
            float sc = st.ga[f] * rsqrtf(st.va[f] + BN_EPS_);
            xob[(size_t)pl * Fc + f] = f2b((hn - st.mu[f]) * sc + st.be[f]);
        }
        __syncthreads();   // zs reads done before next chunk's overwrite
    }
}

// ---------------------------------------------------------------------------
// Conv3D (3x3x3 SAME) + bias + sigmoid, bf16 in, fp32 out.
// Round-0 proven body (80 us, 66% VALUBusy); expf -> __expf. Launched as TWO
// 1280-block dispatches (b_base 0, 8) so each half (~42 us) ranks BELOW
// diag_step (~50 us) in the rocprof top-5 -> diag counters finally visible.
// Per-XCD locality: all blocks with bid%8==k handle batch image b_base+k
// (4 MB of X = one XCD's L2).
// ---------------------------------------------------------------------------
__global__ __launch_bounds__(320) void conv3d_sig_bf16(
    const u16* __restrict__ X,        // bf16 [B,T,1600,40]
    const float* __restrict__ W3,     // [3,3,3,40,1]
    const float* __restrict__ b3,
    float* __restrict__ out,          // [B,T,1600]
    int b_base)
{
    __shared__ float ws[27 * Fc];
    for (int i = threadIdx.x; i < 27 * Fc; i += 320) ws[i] = W3[i];
    __syncthreads();

    const int bid   = blockIdx.x;           // 1280 blocks
    const int xcd   = bid & 7;
    const int local = bid >> 3;             // 0..159
    const int b     = b_base + xcd;
    const int t     = local / 5;
    const int s     = local - t * 5;
    const int pix   = s * 320 + threadIdx.x;
    const int y     = pix / 40;
    const int x     = pix - y * 40;

    float acc = b3[0];
    for (int dt = 0; dt < 3; ++dt) {
        int tc = t + dt - 1;
        if (tc < 0 || tc >= Tt) continue;
        for (int dy = 0; dy < 3; ++dy) {
            int yy = y + dy - 1;
            if (yy < 0 || yy >= Hh) continue;
            for (int dx = 0; dx < 3; ++dx) {
                int xx = x + dx - 1;
                if (xx < 0 || xx >= Ww) continue;
                const u16* xp = X + ((size_t)(b * Tt + tc) * 1600 + yy * 40 + xx) * Fc;
                const float* wp = ws + ((dt * 3 + dy) * 3 + dx) * Fc;
#pragma unroll
                for (int c4 = 0; c4 < Fc; c4 += 4) {
                    ushort4 v = *reinterpret_cast<const ushort4*>(xp + c4);
                    acc = fmaf(b2f(v.x), wp[c4 + 0], acc);
                    acc = fmaf(b2f(v.y), wp[c4 + 1], acc);
                    acc = fmaf(b2f(v.z), wp[c4 + 2], acc);
                    acc = fmaf(b2f(v.w), wp[c4 + 3], acc);
                }
            }
        }
    }
    out[((size_t)(b * Tt + t) * 1600 + pix)] = 1.0f / (1.0f + __expf(-acc));
}

// ---------------------------------------------------------------------------
extern "C" void kernel_launch(void* const* d_in, const int* in_sizes, int n_in,
                              void* d_out, int out_size, void* d_ws, size_t ws_size,
                              hipStream_t stream)
{
    const float* inp = (const float*)d_in[0];

    char* p = (char*)d_ws;
    const size_t x3sz   = (size_t)Bc * Tt * 1600 * Fc * sizeof(u16);  // 65,536,000
    const size_t slotsz = (size_t)Bc * 1600 * Fc * sizeof(u16);       //  2,048,000
    const size_t csz    = (size_t)NPIX * Fc * sizeof(float);          //  4,096,000
    const size_t wfsz   = (size_t)2 * 24 * 5 * 64 * 8 * sizeof(u16);  //    245,760

    u16* X3 = (u16*)p;                       p += x3sz;
    u16* xr[3];
    for (int l = 0; l < 3; ++l) { xr[l] = (u16*)p; p += 2 * slotsz; }
    u16* hb[8];
    for (int i = 0; i < 8; ++i) { hb[i] = (u16*)p; p += slotsz; }
    float* cbuf[4];
    for (int l = 0; l < 4; ++l) { cbuf[l] = (float*)p; p += csz; }
    u16* wf[4];
    for (int l = 0; l < 4; ++l) { wf[l] = (u16*)p; p += wfsz; }
    // total ~112 MB

    for (int l = 0; l < 4; ++l) {
        const float* Wx = (const float*)d_in[1 + 7 * l + 0];
        const float* Wh = (const float*)d_in[1 + 7 * l + 1];
        if (l == 0)
            build_wf<8, 1, 14><<<(2 * 14 * 5 * 512 + 255) / 256, 256, 0, stream>>>(Wx, Wh, wf[l]);
        else
            build_wf<40, 40, 24><<<(2 * 24 * 5 * 512 + 255) / 256, 256, 0, stream>>>(Wx, Wh, wf[l]);
        hipMemsetAsync(hb[l * 2], 0, slotsz, stream);
        hipMemsetAsync(cbuf[l], 0, csz, stream);
    }

    // ---- 35 diagonals: d = l + t ----
    for (int d = 0; d < Tt + 3; ++d) {
        DiagArgs da;
        int na = 0;
        for (int l = 0; l < 4; ++l) {
            int t = d - l;
            if (t < 0 || t >= Tt) continue;
            Stage& s = da.s[na++];
            s.layer = l; s.t = t;
            s.hin  = hb[l * 2 + (t & 1)];
            s.hout = hb[l * 2 + ((t + 1) & 1)];
            s.cst  = cbuf[l];
            s.wf   = wf[l];
            s.bias = (const float*)d_in[1 + 7 * l + 2];
            s.ga   = (const float*)d_in[1 + 7 * l + 3];
            s.be   = (const float*)d_in[1 + 7 * l + 4];
            s.mu   = (const float*)d_in[1 + 7 * l + 5];
            s.va   = (const float*)d_in[1 + 7 * l + 6];
            s.xin  = (l == 0) ? (const void*)inp
                              : (const void*)(xr[l - 1] + (size_t)(t & 1) * (slotsz / 2));
            s.xout = (l == 3) ? X3 : xr[l] + (size_t)(t & 1) * (slotsz / 2);
        }
        diag_step<<<na * 160, 256, 0, stream>>>(da);
    }

    conv3d_sig_bf16<<<1280, 320, 0, stream>>>(
        X3, (const float*)d_in[29], (const float*)d_in[30], (float*)d_out, 0);
    conv3d_sig_bf16<<<1280, 320, 0, stream>>>(
        X3, (const float*)d_in[29], (const float*)d_in[30], (float*)d_out, 8);
}

// Round 6
// 1362.661 us; speedup vs baseline: 1.7422x; 1.2390x over previous
//
#include <hip/hip_runtime.h>
#include <hip/hip_bf16.h>
#include <cstddef>

typedef __attribute__((ext_vector_type(8))) short short8;
typedef __attribute__((ext_vector_type(4))) float f32x4;
typedef unsigned short u16;
typedef unsigned int u32;

#define Bc 16
#define Tt 32
#define Hh 40
#define Ww 40
#define Fc 40
#define NPIX (Bc*Hh*Ww)   // 25600
#define BN_EPS_ 1e-3f

__device__ __forceinline__ float hsig(float x) {
    return fminf(fmaxf(0.2f * x + 0.5f, 0.0f), 1.0f);
}
__device__ __forceinline__ u16 f2b(float f) {
    __hip_bfloat16 h = __float2bfloat16(f);
    return __builtin_bit_cast(u16, h);
}
__device__ __forceinline__ float b2f(u16 u) {
    return __builtin_bit_cast(float, (u32)u << 16);
}
// fast tanh: 1 - 2/(e^2x + 1). x=+inf -> 1, x=-inf -> -1; abs err ~1e-6,
// far below the bf16-granularity test threshold. Replaces libm tanhf.
__device__ __forceinline__ float ftanh(float x) {
    float e = __expf(2.0f * x);
    return 1.0f - __fdividef(2.0f, e + 1.0f);
}

// ---------------------------------------------------------------------------
// Pack [Wx ; Wh] -> bf16 weights in per-wave MFMA B-fragment order:
//   idx = ((((ng*NKO2 + step)*5 + nt)*64 + lane)*8 + j)
//   n = ng*80 + nt*16 + (lane&15);  k = step*32 + (lane>>4)*8 + j
//   k -> pos = k/KPOS, cc = k%KPOS; cc<XPAD -> Wx[pos][cc][n] else Wh[pos][cc-XPAD][n]
// A wave's B-fragment load becomes ONE coalesced global_load_dwordx4.
// ---------------------------------------------------------------------------
template <int XPAD, int CIN, int NKO2>
__global__ __launch_bounds__(256) void build_wf(const float* __restrict__ Wx,
                                                const float* __restrict__ Wh,
                                                u16* __restrict__ Wf)
{
    constexpr int KPOS = XPAD + Fc;
    constexpr int K    = 9 * KPOS;
    int idx = blockIdx.x * 256 + threadIdx.x;
    if (idx >= 2 * NKO2 * 5 * 64 * 8) return;
    int j    = idx & 7;
    int lane = (idx >> 3) & 63;
    int rest = idx >> 9;
    int nt   = rest % 5;  rest /= 5;
    int step = rest % NKO2; rest /= NKO2;
    int ng   = rest;
    int n = ng * 80 + nt * 16 + (lane & 15);
    int k = step * 32 + (lane >> 4) * 8 + j;
    float v = 0.0f;
    if (k < K) {
        int pos = k / KPOS, cc = k - pos * KPOS;
        if (cc < XPAD) {
            v = (cc < CIN) ? Wx[(pos * CIN + cc) * 160 + n] : 0.0f;
        } else {
            v = Wh[(pos * Fc + (cc - XPAD)) * 160 + n];
        }
    }
    Wf[idx] = f2b(v);
}

// ---------------------------------------------------------------------------
// Barrier-free K-loop: B fragments streamed from L2 (coalesced dwordx4),
// A fragments from LDS halo. 25 MFMA per step, no __syncthreads inside.
// Proven structure — DO NOT restructure (round-1 regression lesson).
// ---------------------------------------------------------------------------
template <int KPOS, int XPAD, int NKO2>
__device__ __forceinline__ void kloop(const u16* __restrict__ Xs,
                                      const u16* __restrict__ Hs,
                                      const u16* __restrict__ wf,
                                      const int* py, const int* px,
                                      int lquad, f32x4 acc[5][5])
{
#pragma unroll 2
    for (int step = 0; step < NKO2; ++step) {
        short8 bfr[5];
#pragma unroll
        for (int nt = 0; nt < 5; ++nt)
            bfr[nt] = *reinterpret_cast<const short8*>(wf + (size_t)(step * 5 + nt) * 512);

        const int k   = step * 32 + lquad * 8;
        const int pos = k / KPOS;             // compile-time KPOS -> magic mul
        const int cc  = k - pos * KPOS;
        short8 afr[5] = {};
        if (pos < 9) {
            const int dy = pos / 3, dx = pos - dy * 3;
            const u16* base; int ch, str;
            if (cc < XPAD) { base = Xs; ch = cc;        str = XPAD; }
            else           { base = Hs; ch = cc - XPAD; str = Fc;   }
#pragma unroll
            for (int mt = 0; mt < 5; ++mt)
                afr[mt] = *reinterpret_cast<const short8*>(
                    &base[((py[mt] + dy) * 42 + px[mt] + dx) * str + ch]);
        }
        __builtin_amdgcn_s_setprio(1);
#pragma unroll
        for (int mt = 0; mt < 5; ++mt)
#pragma unroll
            for (int nt = 0; nt < 5; ++nt)
                acc[mt][nt] = __builtin_amdgcn_mfma_f32_16x16x32_bf16(
                    afr[mt], bfr[nt], acc[mt][nt], 0, 0, 0);
        __builtin_amdgcn_s_setprio(0);
    }
}

// ---------------------------------------------------------------------------
// Diagonal-pipelined ConvLSTM step: up to 4 (layer,t) stages per launch.
// Per stage: 160 blocks, M-tile 160 pixels (4 rows), N=160 gates.
// ---------------------------------------------------------------------------
struct Stage {
    const void* xin;   // l==0: fp32 input base; l>=1: bf16 X-ring slot
    const u16* hin;    // bf16 [NPIX][40]
    u16*       hout;
    float*     cst;    // fp32 [NPIX][40]
    const u16* wf;     // fragment-ordered weights
    const float* bias; const float* ga; const float* be;
    const float* mu;   const float* va;
    u16*       xout;
    int layer; int t;
};
struct DiagArgs { Stage s[4]; };

__global__ __launch_bounds__(256, 3) void diag_step(DiagArgs args)
{
    // max(halo 40320 B, zs 80*164*4 = 52480 B) + ctab 1120 B = 53.6 KB
    // 3 x 53600 = 160.8 KB <= 163.84 KB LDS/CU  => 3 blocks/CU preserved
    __shared__ __align__(16) u16 smem[26240];
    __shared__ __align__(16) float ctab[280];   // [0:160) bias, [160:200) sc,
                                                // [200:240) mu, [240:280) be

    const int sidx = blockIdx.x / 160;
    const int blk  = blockIdx.x - sidx * 160;
    const Stage& st = args.s[sidx];
    const int l    = st.layer;
    const int XPAD = (l == 0) ? 8 : 40;

    u16* Xs = smem;
    u16* Hs = smem + 6 * 42 * XPAD;
    float* zs = reinterpret_cast<float*>(smem);   // epilogue overlay

    const int tid   = threadIdx.x;
    const int P0    = blk * 160;
    const int bimg  = P0 / 1600;
    const int P0l   = P0 - bimg * 1600;
    const int P0row = P0l / 40;            // 0,4,...,36

    // ---- per-f epilogue constants (computed once, not per element) ----
    if (tid < 40) {
        ctab[tid]       = st.bias[tid];
        ctab[40 + tid]  = st.bias[40 + tid];
        ctab[80 + tid]  = st.bias[80 + tid];
        ctab[120 + tid] = st.bias[120 + tid];
        ctab[160 + tid] = st.ga[tid] * rsqrtf(st.va[tid] + BN_EPS_);
        ctab[200 + tid] = st.mu[tid];
        ctab[240 + tid] = st.be[tid];
    }

    // ---- stage Hs halo: 6 rows x 42 cols x 40 ch (uint4: 16 B/lane) ----
    const u16* hp = st.hin + (size_t)bimg * 1600 * Fc;
    for (int i = tid; i < 6 * 40 * 5; i += 256) {
        int s = i / 200, rem = i - s * 200;
        int px_ = rem / 5, c8 = rem - px_ * 5;
        int gy = P0row - 1 + s;
        uint4 v = make_uint4(0u, 0u, 0u, 0u);
        if (gy >= 0 && gy < Hh)
            v = *reinterpret_cast<const uint4*>(hp + ((size_t)gy * Ww + px_) * Fc + c8 * 8);
        *reinterpret_cast<uint4*>(&Hs[(s * 42 + px_ + 1) * Fc + c8 * 8]) = v;
    }
    for (int i = tid; i < 6 * 2 * 5; i += 256) {
        int s = i / 10, rem = i - s * 10;
        int side = rem / 5, c8 = rem - side * 5;
        *reinterpret_cast<uint4*>(&Hs[(s * 42 + (side ? 41 : 0)) * Fc + c8 * 8]) =
            make_uint4(0u, 0u, 0u, 0u);
    }

    // ---- stage Xs halo ----
    if (l == 0) {
        const float* xf = (const float*)st.xin + (size_t)(bimg * Tt + st.t) * 1600;
        for (int i = tid; i < 6 * 42; i += 256) {
            int s = i / 42, xc = i - s * 42;
            int gy = P0row - 1 + s, gx = xc - 1;
            u16 tmp[8] = {0, 0, 0, 0, 0, 0, 0, 0};
            if (gy >= 0 && gy < Hh && gx >= 0 && gx < Ww)
                tmp[0] = f2b(xf[(size_t)gy * Ww + gx]);
            *reinterpret_cast<uint4*>(&Xs[(s * 42 + xc) * 8]) =
                *reinterpret_cast<const uint4*>(tmp);
        }
    } else {
        const u16* xb = (const u16*)st.xin + (size_t)bimg * 1600 * Fc;
        for (int i = tid; i < 6 * 40 * 5; i += 256) {
            int s = i / 200, rem = i - s * 200;
            int px_ = rem / 5, c8 = rem - px_ * 5;
            int gy = P0row - 1 + s;
            uint4 v = make_uint4(0u, 0u, 0u, 0u);
            if (gy >= 0 && gy < Hh)
                v = *reinterpret_cast<const uint4*>(xb + ((size_t)gy * Ww + px_) * Fc + c8 * 8);
            *reinterpret_cast<uint4*>(&Xs[(s * 42 + px_ + 1) * Fc + c8 * 8]) = v;
        }
        for (int i = tid; i < 6 * 2 * 5; i += 256) {
            int s = i / 10, rem = i - s * 10;
            int side = rem / 5, c8 = rem - side * 5;
            *reinterpret_cast<uint4*>(&Xs[(s * 42 + (side ? 41 : 0)) * Fc + c8 * 8]) =
                make_uint4(0u, 0u, 0u, 0u);
        }
    }

    // ---- wave constants ----
    const int lane  = tid & 63;
    const int wid   = tid >> 6;
    const int mg    = wid & 1;
    const int ng    = wid >> 1;
    const int lcol  = lane & 15;
    const int lquad = lane >> 4;

    int py[5], px[5];
#pragma unroll
    for (int mt = 0; mt < 5; ++mt) {
        int mrow = mg * 80 + mt * 16 + lcol;
        py[mt] = mrow / 40;
        px[mt] = mrow - py[mt] * 40;
    }

    f32x4 acc[5][5] = {};

    __syncthreads();   // halos + ctab staged; K-loop is barrier-free

    if (l == 0) {
        const u16* wf = st.wf + ((size_t)ng * 14 * 5 + 0) * 512 + (size_t)lane * 8;
        kloop<48, 8, 14>(Xs, Hs, wf, py, px, lquad, acc);
    } else {
        const u16* wf = st.wf + ((size_t)ng * 24 * 5 + 0) * 512 + (size_t)lane * 8;
        kloop<80, 40, 24>(Xs, Hs, wf, py, px, lquad, acc);
    }

    __syncthreads();   // all waves done reading halo LDS before zs overlay

    // ---- epilogue in two 80-row chunks (zs overlays smem) ----
    // paired-f processing: float2 zs/c reads, float2 c write, packed u32
    // bf16 stores -> half the iterations and memory instructions.
    u16* hob = st.hout;
    float* cb = st.cst;
    u16* xob = (l == 3)
        ? st.xout + ((size_t)(bimg * Tt + st.t) * 1600 + P0l) * Fc
        : st.xout + ((size_t)bimg * 1600 + P0l) * Fc;

    for (int q = 0; q < 2; ++q) {
        if (mg == q) {
#pragma unroll
            for (int mt = 0; mt < 5; ++mt)
#pragma unroll
                for (int nt = 0; nt < 5; ++nt) {
                    int mr   = mt * 16 + lquad * 4;
                    int ncol = ng * 80 + nt * 16 + lcol;
#pragma unroll
                    for (int r = 0; r < 4; ++r)
                        zs[(mr + r) * 164 + ncol] = acc[mt][nt][r];
                }
        }
        __syncthreads();
        for (int i = tid; i < 1600; i += 256) {
            int m = i / 20, fp = i - m * 20;
            int f = fp * 2;
            const float2 vi = *reinterpret_cast<const float2*>(&zs[m * 164 + f]);
            const float2 vf = *reinterpret_cast<const float2*>(&zs[m * 164 + 40 + f]);
            const float2 vg = *reinterpret_cast<const float2*>(&zs[m * 164 + 80 + f]);
            const float2 vo = *reinterpret_cast<const float2*>(&zs[m * 164 + 120 + f]);
            const float2 bi  = *reinterpret_cast<const float2*>(&ctab[f]);
            const float2 bf_ = *reinterpret_cast<const float2*>(&ctab[40 + f]);
            const float2 bg  = *reinterpret_cast<const float2*>(&ctab[80 + f]);
            const float2 bo  = *reinterpret_cast<const float2*>(&ctab[120 + f]);
            const float2 sc2 = *reinterpret_cast<const float2*>(&ctab[160 + f]);
            const float2 mu2 = *reinterpret_cast<const float2*>(&ctab[200 + f]);
            const float2 be2 = *reinterpret_cast<const float2*>(&ctab[240 + f]);
            int pl = q * 80 + m;
            size_t gp = (size_t)(P0 + pl) * Fc + f;
            const float2 co = *reinterpret_cast<const float2*>(&cb[gp]);
            float cnx = hsig(vf.x + bf_.x) * co.x + hsig(vi.x + bi.x) * ftanh(vg.x + bg.x);
            float cny = hsig(vf.y + bf_.y) * co.y + hsig(vi.y + bi.y) * ftanh(vg.y + bg.y);
            float hnx = hsig(vo.x + bo.x) * ftanh(cnx);
            float hny = hsig(vo.y + bo.y) * ftanh(cny);
            *reinterpret_cast<float2*>(&cb[gp]) = make_float2(cnx, cny);
            u32 hpk = (u32)f2b(hnx) | ((u32)f2b(hny) << 16);
            *reinterpret_cast<u32*>(&hob[gp]) = hpk;
            float xnx = (hnx - mu2.x) * sc2.x + be2.x;
            float xny = (hny - mu2.y) * sc2.y + be2.y;
            u32 xpk = (u32)f2b(xnx) | ((u32)f2b(xny) << 16);
            *reinterpret_cast<u32*>(&xob[(size_t)pl * Fc + f]) = xpk;
        }
        __syncthreads();   // zs reads done before next chunk's overwrite
    }
}

// ---------------------------------------------------------------------------
// Conv3D (3x3x3 SAME) + bias + sigmoid, bf16 in, fp32 out.
// Round-0 proven body; __expf. Two 1280-block dispatches (b_base 0, 8).
// ---------------------------------------------------------------------------
__global__ __launch_bounds__(320) void conv3d_sig_bf16(
    const u16* __restrict__ X,        // bf16 [B,T,1600,40]
    const float* __restrict__ W3,     // [3,3,3,40,1]
    const float* __restrict__ b3,
    float* __restrict__ out,          // [B,T,1600]
    int b_base)
{
    __shared__ float ws[27 * Fc];
    for (int i = threadIdx.x; i < 27 * Fc; i += 320) ws[i] = W3[i];
    __syncthreads();

    const int bid   = blockIdx.x;           // 1280 blocks
    const int xcd   = bid & 7;
    const int local = bid >> 3;             // 0..159
    const int b     = b_base + xcd;
    const int t     = local / 5;
    const int s     = local - t * 5;
    const int pix   = s * 320 + threadIdx.x;
    const int y     = pix / 40;
    const int x     = pix - y * 40;

    float acc = b3[0];
    for (int dt = 0; dt < 3; ++dt) {
        int tc = t + dt - 1;
        if (tc < 0 || tc >= Tt) continue;
        for (int dy = 0; dy < 3; ++dy) {
            int yy = y + dy - 1;
            if (yy < 0 || yy >= Hh) continue;
            for (int dx = 0; dx < 3; ++dx) {
                int xx = x + dx - 1;
                if (xx < 0 || xx >= Ww) continue;
                const u16* xp = X + ((size_t)(b * Tt + tc) * 1600 + yy * 40 + xx) * Fc;
                const float* wp = ws + ((dt * 3 + dy) * 3 + dx) * Fc;
#pragma unroll
                for (int c4 = 0; c4 < Fc; c4 += 4) {
                    ushort4 v = *reinterpret_cast<const ushort4*>(xp + c4);
                    acc = fmaf(b2f(v.x), wp[c4 + 0], acc);
                    acc = fmaf(b2f(v.y), wp[c4 + 1], acc);
                    acc = fmaf(b2f(v.z), wp[c4 + 2], acc);
                    acc = fmaf(b2f(v.w), wp[c4 + 3], acc);
                }
            }
        }
    }
    out[((size_t)(b * Tt + t) * 1600 + pix)] = 1.0f / (1.0f + __expf(-acc));
}

// ---------------------------------------------------------------------------
extern "C" void kernel_launch(void* const* d_in, const int* in_sizes, int n_in,
                              void* d_out, int out_size, void* d_ws, size_t ws_size,
                              hipStream_t stream)
{
    const float* inp = (const float*)d_in[0];

    char* p = (char*)d_ws;
    const size_t x3sz   = (size_t)Bc * Tt * 1600 * Fc * sizeof(u16);  // 65,536,000
    const size_t slotsz = (size_t)Bc * 1600 * Fc * sizeof(u16);       //  2,048,000
    const size_t csz    = (size_t)NPIX * Fc * sizeof(float);          //  4,096,000
    const size_t wfsz   = (size_t)2 * 24 * 5 * 64 * 8 * sizeof(u16);  //    245,760

    u16* X3 = (u16*)p;                       p += x3sz;
    u16* xr[3];
    for (int l = 0; l < 3; ++l) { xr[l] = (u16*)p; p += 2 * slotsz; }
    u16* hb[8];
    for (int i = 0; i < 8; ++i) { hb[i] = (u16*)p; p += slotsz; }
    float* cbuf[4];
    for (int l = 0; l < 4; ++l) { cbuf[l] = (float*)p; p += csz; }
    u16* wf[4];
    for (int l = 0; l < 4; ++l) { wf[l] = (u16*)p; p += wfsz; }
    // total ~112 MB

    for (int l = 0; l < 4; ++l) {
        const float* Wx = (const float*)d_in[1 + 7 * l + 0];
        const float* Wh = (const float*)d_in[1 + 7 * l + 1];
        if (l == 0)
            build_wf<8, 1, 14><<<(2 * 14 * 5 * 512 + 255) / 256, 256, 0, stream>>>(Wx, Wh, wf[l]);
        else
            build_wf<40, 40, 24><<<(2 * 24 * 5 * 512 + 255) / 256, 256, 0, stream>>>(Wx, Wh, wf[l]);
        hipMemsetAsync(hb[l * 2], 0, slotsz, stream);
        hipMemsetAsync(cbuf[l], 0, csz, stream);
    }

    // ---- 35 diagonals: d = l + t ----
    for (int d = 0; d < Tt + 3; ++d) {
        DiagArgs da;
        int na = 0;
        for (int l = 0; l < 4; ++l) {
            int t = d - l;
            if (t < 0 || t >= Tt) continue;
            Stage& s = da.s[na++];
            s.layer = l; s.t = t;
            s.hin  = hb[l * 2 + (t & 1)];
            s.hout = hb[l * 2 + ((t + 1) & 1)];
            s.cst  = cbuf[l];
            s.wf   = wf[l];
            s.bias = (const float*)d_in[1 + 7 * l + 2];
            s.ga   = (const float*)d_in[1 + 7 * l + 3];
            s.be   = (const float*)d_in[1 + 7 * l + 4];
            s.mu   = (const float*)d_in[1 + 7 * l + 5];
            s.va   = (const float*)d_in[1 + 7 * l + 6];
            s.xin  = (l == 0) ? (const void*)inp
                              : (const void*)(xr[l - 1] + (size_t)(t & 1) * (slotsz / 2));
            s.xout = (l == 3) ? X3 : xr[l] + (size_t)(t & 1) * (slotsz / 2);
        }
        diag_step<<<na * 160, 256, 0, stream>>>(da);
    }

    conv3d_sig_bf16<<<1280, 320, 0, stream>>>(
        X3, (const float*)d_in[29], (const float*)d_in[30], (float*)d_out, 0);
    conv3d_sig_bf16<<<1280, 320, 0, stream>>>(
        X3, (const float*)d_in[29], (const float*)d_in[30], (float*)d_out, 8);
}